// Round 3
// baseline (212.832 us; speedup 1.0000x reference)
//
#include <hip/hip_runtime.h>

#define LL 8
#define NN 100000
#define HH 128
#define KT 1024
#define BM 64
#define NNHH (NN * HH)

typedef __attribute__((ext_vector_type(4))) float f32x4;
typedef __attribute__((ext_vector_type(8))) short bf16x8;
typedef __attribute__((ext_vector_type(8))) unsigned short u16x8;

__device__ __forceinline__ unsigned short f2bf(float f) {
    unsigned u = __float_as_uint(f);
    unsigned r = ((u >> 16) & 1u) + 0x7fffu;   // RNE
    return (unsigned short)((u + r) >> 16);
}

// Pre-pack w_ref (f32 [128 cols][1024 k]) -> bf16 in fragment order:
// wp[(k8*128 + col)*8 + e] = bf16(w_ref[col][k8*8+e]),  k8 = k/8.
__global__ __launch_bounds__(256) void pack_w_kernel(const float* __restrict__ w_ref,
                                                     unsigned short* __restrict__ wp) {
    int gid = blockIdx.x * 256 + threadIdx.x;   // 0..16383
    int col = gid >> 7;
    int k8  = gid & 127;
    const float* s = w_ref + (size_t)col * KT + (size_t)k8 * 8;
    float4 v0 = *reinterpret_cast<const float4*>(s);
    float4 v1 = *reinterpret_cast<const float4*>(s + 4);
    u16x8 p;
    p[0] = f2bf(v0.x); p[1] = f2bf(v0.y); p[2] = f2bf(v0.z); p[3] = f2bf(v0.w);
    p[4] = f2bf(v1.x); p[5] = f2bf(v1.y); p[6] = f2bf(v1.z); p[7] = f2bf(v1.w);
    *reinterpret_cast<u16x8*>(wp + (size_t)(k8 * 128 + col) * 8) = p;
}

// m-split, barrier-free K-loop:
//  Block = 64 nodes, 4 waves; wave w owns nodes [n0+w*16, +16), ALL 128 cols.
//  A fragments: global->reg f32 loads (depth-2 prefetch), convert to bf16 in reg.
//  B fragments: global->reg from packed bf16 wp (L2-resident), fragment-ordered.
//  No LDS staging, no barriers in the K-loop. One barrier before the epilogue.
__global__ __launch_bounds__(256, 3)
void gamlp_main(const float* __restrict__ xs,
                const unsigned short* __restrict__ wp,
                const float* __restrict__ b_ref,
                const float* __restrict__ w_att,
                const float* __restrict__ b_att_p,
                const float* __restrict__ alpha_p,
                float* __restrict__ out)
{
    __shared__ float sjk_lds[BM];

    const int tid  = threadIdx.x;
    const int lane = tid & 63;
    const int wave = tid >> 6;
    const int colq = lane & 15;     // A row index (node) / B col-within-frag
    const int kq   = lane >> 4;     // k-chunk 0..3
    const int n0   = blockIdx.x * BM;

    const float alpha = *alpha_p;
    const float batt  = *b_att_p;

    // A: this lane loads node row (n0 + wave*16 + colq), k-bytes kq*8.. per c
    const int arow = min(n0 + wave * 16 + colq, NN - 1);
    const float* aptr = xs + (size_t)arow * HH + kq * 8;
    // B: fragment base for this lane
    const unsigned short* bp0 = wp + (size_t)kq * 1024 + colq * 8;

    f32x4 acc[8];
    #pragma unroll
    for (int n = 0; n < 8; n++) acc[n] = (f32x4){0.f, 0.f, 0.f, 0.f};

    // software-pipelined A prefetch, depth 2
    f32x4 A0[4], A1[4], A2[4];
    {
        const float* p = aptr;                   // step 0: l=0, h0=0
        A0[0] = *reinterpret_cast<const f32x4*>(p);
        A0[1] = *reinterpret_cast<const f32x4*>(p + 4);
        A0[2] = *reinterpret_cast<const f32x4*>(p + 32);
        A0[3] = *reinterpret_cast<const f32x4*>(p + 36);
        p = aptr + 64;                           // step 1: l=0, h0=64
        A1[0] = *reinterpret_cast<const f32x4*>(p);
        A1[1] = *reinterpret_cast<const f32x4*>(p + 4);
        A1[2] = *reinterpret_cast<const f32x4*>(p + 32);
        A1[3] = *reinterpret_cast<const f32x4*>(p + 36);
    }

    #pragma unroll
    for (int step = 0; step < 16; ++step) {
        if (step < 14) {
            const int s = step + 2;
            const float* p = aptr + (size_t)(s >> 1) * NNHH + (s & 1) * 64;
            A2[0] = *reinterpret_cast<const f32x4*>(p);
            A2[1] = *reinterpret_cast<const f32x4*>(p + 4);
            A2[2] = *reinterpret_cast<const f32x4*>(p + 32);
            A2[3] = *reinterpret_cast<const f32x4*>(p + 36);
        }
        // convert current A regs -> two bf16 fragments (c=0: k 0..31, c=1: k 32..63)
        u16x8 af0, af1;
        #pragma unroll
        for (int e = 0; e < 4; e++) {
            af0[e]     = f2bf(A0[0][e]);
            af0[e + 4] = f2bf(A0[1][e]);
            af1[e]     = f2bf(A0[2][e]);
            af1[e + 4] = f2bf(A0[3][e]);
        }
        const unsigned short* pb = bp0 + (size_t)step * 8192;   // 8 k8-rows/step * 1024
        #pragma unroll
        for (int n = 0; n < 8; n++) {
            bf16x8 b0 = *reinterpret_cast<const bf16x8*>(pb + n * 128);
            bf16x8 b1 = *reinterpret_cast<const bf16x8*>(pb + 4096 + n * 128);
            acc[n] = __builtin_amdgcn_mfma_f32_16x16x32_bf16(
                reinterpret_cast<bf16x8&>(af0), b0, acc[n], 0, 0, 0);
            acc[n] = __builtin_amdgcn_mfma_f32_16x16x32_bf16(
                reinterpret_cast<bf16x8&>(af1), b1, acc[n], 0, 0, 0);
        }
        #pragma unroll
        for (int e = 0; e < 4; e++) { A0[e] = A1[e]; A1[e] = A2[e]; }
    }

    // ---- sjk: sum over 128 cols of prelu(jk + b_ref) * wa_ref ----
    // D layout: col = n*16 + colq, node = wave*16 + kq*4 + r
    float s3[4];
    #pragma unroll
    for (int r = 0; r < 4; r++) {
        float s = 0.f;
        #pragma unroll
        for (int n = 0; n < 8; n++) {
            float v = acc[n][r] + b_ref[n * 16 + colq];
            v = (v >= 0.f) ? v : alpha * v;
            s += v * w_att[n * 16 + colq];
        }
        s += __shfl_xor(s, 1);
        s += __shfl_xor(s, 2);
        s += __shfl_xor(s, 4);
        s += __shfl_xor(s, 8);
        s3[r] = s;
    }
    if (colq == 0) {
        #pragma unroll
        for (int r = 0; r < 4; r++)
            sjk_lds[wave * 16 + kq * 4 + r] = s3[r];
    }
    __syncthreads();

    // ---- fused epilogue: s_x (f32) + relu scores + softmax + weighted sum ----
    #pragma unroll
    for (int i = 0; i < 8; i++) {
        int f = tid + i * 256;          // 0..2047
        int node = f >> 5;              // 0..63
        int q = (f & 31) << 2;          // 0..124
        int ng = n0 + node;
        int ngc = min(ng, NN - 1);
        const float* base = xs + (size_t)ngc * HH + q;
        f32x4 wv = *reinterpret_cast<const f32x4*>(w_att + HH + q);
        f32x4 v[LL];
        float sx[LL];
        #pragma unroll
        for (int l = 0; l < LL; l++) {
            v[l] = *reinterpret_cast<const f32x4*>(base + (size_t)l * NNHH);
            sx[l] = v[l][0] * wv[0] + v[l][1] * wv[1] + v[l][2] * wv[2] + v[l][3] * wv[3];
        }
        #pragma unroll
        for (int l = 0; l < LL; l++) {
            float s = sx[l];
            s += __shfl_xor(s, 1);
            s += __shfl_xor(s, 2);
            s += __shfl_xor(s, 4);
            s += __shfl_xor(s, 8);
            s += __shfl_xor(s, 16);
            sx[l] = s;
        }
        float sjk = sjk_lds[node];
        float sc[LL], mx = 0.f;
        #pragma unroll
        for (int l = 0; l < LL; l++) {
            float s = sjk + sx[l] + batt;
            s = fmaxf(s, 0.f);
            sc[l] = s;
            mx = fmaxf(mx, s);
        }
        float den = 0.f;
        #pragma unroll
        for (int l = 0; l < LL; l++) { sc[l] = __expf(sc[l] - mx); den += sc[l]; }
        float inv = 1.f / den;
        f32x4 o = (f32x4){0.f, 0.f, 0.f, 0.f};
        #pragma unroll
        for (int l = 0; l < LL; l++) o += (sc[l] * inv) * v[l];
        if (ng < NN)
            *reinterpret_cast<f32x4*>(out + (size_t)ng * HH + q) = o;
    }
}

extern "C" void kernel_launch(void* const* d_in, const int* in_sizes, int n_in,
                              void* d_out, int out_size, void* d_ws, size_t ws_size,
                              hipStream_t stream) {
    const float* xs     = (const float*)d_in[0];
    const float* w_ref  = (const float*)d_in[1];
    const float* b_ref  = (const float*)d_in[2];
    const float* w_att  = (const float*)d_in[3];
    const float* b_att  = (const float*)d_in[4];
    const float* alpha  = (const float*)d_in[5];
    float* out = (float*)d_out;
    unsigned short* wp = (unsigned short*)d_ws;   // 256 KB packed bf16 weights

    pack_w_kernel<<<64, 256, 0, stream>>>(w_ref, wp);
    const int grid = (NN + BM - 1) / BM;          // 1563
    gamlp_main<<<grid, 256, 0, stream>>>(xs, wp, b_ref, w_att, b_att, alpha, out);
}

// Round 4
// 163.917 us; speedup vs baseline: 1.2984x; 1.2984x over previous
//
#include <hip/hip_runtime.h>

#define LL 8
#define NN 100000
#define HH 128
#define KT 1024
#define BM 64
#define NNHH (NN * HH)

typedef __attribute__((ext_vector_type(4))) float f32x4;
typedef __attribute__((ext_vector_type(8))) short bf16x8;
typedef __attribute__((ext_vector_type(8))) unsigned short u16x8;

__device__ __forceinline__ unsigned short f2bf(float f) {
    unsigned u = __float_as_uint(f);
    unsigned r = ((u >> 16) & 1u) + 0x7fffu;   // RNE
    return (unsigned short)((u + r) >> 16);
}

// Pre-pack w_ref (f32 [128 cols][1024 k]) -> bf16 in fragment order:
// wp[(k8*128 + col)*8 + e] = bf16(w_ref[col][k8*8+e]),  k8 = k/8.
__global__ __launch_bounds__(256) void pack_w_kernel(const float* __restrict__ w_ref,
                                                     unsigned short* __restrict__ wp) {
    int gid = blockIdx.x * 256 + threadIdx.x;   // 0..16383
    int col = gid >> 7;
    int k8  = gid & 127;
    const float* s = w_ref + (size_t)col * KT + (size_t)k8 * 8;
    float4 v0 = *reinterpret_cast<const float4*>(s);
    float4 v1 = *reinterpret_cast<const float4*>(s + 4);
    u16x8 p;
    p[0] = f2bf(v0.x); p[1] = f2bf(v0.y); p[2] = f2bf(v0.z); p[3] = f2bf(v0.w);
    p[4] = f2bf(v1.x); p[5] = f2bf(v1.y); p[6] = f2bf(v1.z); p[7] = f2bf(v1.w);
    *reinterpret_cast<u16x8*>(wp + (size_t)(k8 * 128 + col) * 8) = p;
}

// Block = 64 nodes, 4 waves; wave w covers all 64 nodes x cols [w*32, w*32+32).
// K-loop: 8 steps of BK=128 (one layer/step), double-buffered A in LDS,
// T14 split staging: issue next-step global loads FIRST, compute current step
// (LDS frags + B global->reg + MFMA), convert+ds_write late, ONE barrier/step.
__global__ __launch_bounds__(256, 3)
void gamlp_main(const float* __restrict__ xs,
                const unsigned short* __restrict__ wp,
                const float* __restrict__ b_ref,
                const float* __restrict__ w_att,
                const float* __restrict__ b_att_p,
                const float* __restrict__ alpha_p,
                float* __restrict__ out)
{
    __shared__ unsigned short A_lds[2][BM * 128];   // 2 x 16 KB, 16-slot XOR swizzle
    __shared__ float sjk_lds[BM][4];

    const int tid  = threadIdx.x;
    const int lane = tid & 63;
    const int wave = tid >> 6;
    const int colq = lane & 15;
    const int kq   = lane >> 4;
    const int n0   = blockIdx.x * BM;

    const float alpha = *alpha_p;
    const float batt  = *b_att_p;

    // ---- staging map: thread covers rows rb+16i (i<4), 16B slot ks ----
    const int ks = tid & 15;
    const int rb = tid >> 4;
    const float* srcp[4];
    unsigned short* dst0p[4];
    unsigned short* dst1p[4];
    #pragma unroll
    for (int i = 0; i < 4; i++) {
        int row = rb + i * 16;
        srcp[i] = xs + (size_t)min(n0 + row, NN - 1) * HH + ks * 8;
        int off = row * 128 + ((ks ^ rb) * 8);     // slot swizzle: ks ^ (row&15)
        dst0p[i] = &A_lds[0][off];
        dst1p[i] = &A_lds[1][off];
    }

    // ---- B fragment pointers (packed bf16, fragment-ordered, L2/L3-resident) ----
    const unsigned short* pB0 = wp + (size_t)(wave * 32 + colq) * 8;
    const unsigned short* pB1 = pB0 + 128;      // +16 cols

    const float wr0 = w_att[wave * 32 + colq],      wr1 = w_att[wave * 32 + 16 + colq];
    const float br0 = b_ref[wave * 32 + colq],      br1 = b_ref[wave * 32 + 16 + colq];

    f32x4 acc[4][2];
    #pragma unroll
    for (int m = 0; m < 4; m++) { acc[m][0] = (f32x4){0,0,0,0}; acc[m][1] = (f32x4){0,0,0,0}; }

    f32x4 pf[8];
    // ---- prologue: stage step 0 into buf 0 ----
    #pragma unroll
    for (int i = 0; i < 4; i++) {
        pf[2*i]   = *reinterpret_cast<const f32x4*>(srcp[i]);
        pf[2*i+1] = *reinterpret_cast<const f32x4*>(srcp[i] + 4);
    }
    #pragma unroll
    for (int i = 0; i < 4; i++) {
        u16x8 p;
        #pragma unroll
        for (int e = 0; e < 4; e++) { p[e] = f2bf(pf[2*i][e]); p[e+4] = f2bf(pf[2*i+1][e]); }
        *reinterpret_cast<u16x8*>(dst0p[i]) = p;
    }
    __syncthreads();

    // ---- main loop: 8 steps of BK=128 ----
    #pragma unroll
    for (int s = 0; s < 8; s++) {
        const int cur = s & 1;
        // (1) T14 issue-early: next step's global loads
        if (s < 7) {
            const size_t g = (size_t)(s + 1) * NNHH;
            #pragma unroll
            for (int i = 0; i < 4; i++) {
                pf[2*i]   = *reinterpret_cast<const f32x4*>(srcp[i] + g);
                pf[2*i+1] = *reinterpret_cast<const f32x4*>(srcp[i] + g + 4);
            }
        }
        // (2) compute current step from LDS + B + MFMA
        const int k8base = s * 16;
        #pragma unroll
        for (int c = 0; c < 4; c++) {
            bf16x8 af[4];
            #pragma unroll
            for (int m = 0; m < 4; m++) {
                int row = m * 16 + colq;
                af[m] = *reinterpret_cast<const bf16x8*>(
                    &A_lds[cur][row * 128 + (((c * 4 + kq) ^ colq) * 8)]);
            }
            const size_t boff = (size_t)(k8base + c * 4 + kq) * 1024;
            bf16x8 b0 = *reinterpret_cast<const bf16x8*>(pB0 + boff);
            bf16x8 b1 = *reinterpret_cast<const bf16x8*>(pB1 + boff);
            #pragma unroll
            for (int m = 0; m < 4; m++) {
                acc[m][0] = __builtin_amdgcn_mfma_f32_16x16x32_bf16(af[m], b0, acc[m][0], 0, 0, 0);
                acc[m][1] = __builtin_amdgcn_mfma_f32_16x16x32_bf16(af[m], b1, acc[m][1], 0, 0, 0);
            }
        }
        // (3) write-late: convert + ds_write into the other buffer
        if (s < 7) {
            #pragma unroll
            for (int i = 0; i < 4; i++) {
                u16x8 p;
                #pragma unroll
                for (int e = 0; e < 4; e++) { p[e] = f2bf(pf[2*i][e]); p[e+4] = f2bf(pf[2*i+1][e]); }
                *reinterpret_cast<u16x8*>((cur ? dst0p : dst1p)[i]) = p;
            }
        }
        __syncthreads();
    }

    // ---- sjk: sum over this wave's 32 cols of prelu(jk + b_ref) * wa_ref ----
    // D layout: col = wave*32 + n*16 + colq, node = m*16 + kq*4 + r
    #pragma unroll
    for (int m = 0; m < 4; m++) {
        float sr[4];
        #pragma unroll
        for (int r = 0; r < 4; r++) {
            float v0 = acc[m][0][r] + br0;  v0 = (v0 >= 0.f) ? v0 : alpha * v0;
            float v1 = acc[m][1][r] + br1;  v1 = (v1 >= 0.f) ? v1 : alpha * v1;
            float sv = v0 * wr0 + v1 * wr1;
            sv += __shfl_xor(sv, 1);
            sv += __shfl_xor(sv, 2);
            sv += __shfl_xor(sv, 4);
            sv += __shfl_xor(sv, 8);
            sr[r] = sv;
        }
        if (colq == 0) {
            #pragma unroll
            for (int r = 0; r < 4; r++)
                sjk_lds[m * 16 + kq * 4 + r][wave] = sr[r];
        }
    }
    __syncthreads();

    // ---- fused epilogue: s_x (f32) + relu scores + softmax + weighted sum ----
    #pragma unroll
    for (int i = 0; i < 8; i++) {
        int f = tid + i * 256;          // 0..2047
        int node = f >> 5;              // 0..63
        int q = (f & 31) << 2;          // 0..124
        int ng = n0 + node;
        int ngc = min(ng, NN - 1);
        const float* base = xs + (size_t)ngc * HH + q;
        f32x4 wv = *reinterpret_cast<const f32x4*>(w_att + HH + q);
        f32x4 v[LL];
        float sx[LL];
        #pragma unroll
        for (int l = 0; l < LL; l++) {
            v[l] = *reinterpret_cast<const f32x4*>(base + (size_t)l * NNHH);
            sx[l] = v[l][0] * wv[0] + v[l][1] * wv[1] + v[l][2] * wv[2] + v[l][3] * wv[3];
        }
        #pragma unroll
        for (int l = 0; l < LL; l++) {
            float sv = sx[l];
            sv += __shfl_xor(sv, 1);
            sv += __shfl_xor(sv, 2);
            sv += __shfl_xor(sv, 4);
            sv += __shfl_xor(sv, 8);
            sv += __shfl_xor(sv, 16);
            sx[l] = sv;
        }
        float sjk = sjk_lds[node][0] + sjk_lds[node][1] + sjk_lds[node][2] + sjk_lds[node][3];
        float sc[LL], mx = 0.f;
        #pragma unroll
        for (int l = 0; l < LL; l++) {
            float sv = sjk + sx[l] + batt;
            sv = fmaxf(sv, 0.f);
            sc[l] = sv;
            mx = fmaxf(mx, sv);
        }
        float den = 0.f;
        #pragma unroll
        for (int l = 0; l < LL; l++) { sc[l] = __expf(sc[l] - mx); den += sc[l]; }
        float inv = 1.f / den;
        f32x4 o = (f32x4){0.f, 0.f, 0.f, 0.f};
        #pragma unroll
        for (int l = 0; l < LL; l++) o += (sc[l] * inv) * v[l];
        if (ng < NN)
            *reinterpret_cast<f32x4*>(out + (size_t)ng * HH + q) = o;
    }
}

extern "C" void kernel_launch(void* const* d_in, const int* in_sizes, int n_in,
                              void* d_out, int out_size, void* d_ws, size_t ws_size,
                              hipStream_t stream) {
    const float* xs     = (const float*)d_in[0];
    const float* w_ref  = (const float*)d_in[1];
    const float* b_ref  = (const float*)d_in[2];
    const float* w_att  = (const float*)d_in[3];
    const float* b_att  = (const float*)d_in[4];
    const float* alpha  = (const float*)d_in[5];
    float* out = (float*)d_out;
    unsigned short* wp = (unsigned short*)d_ws;   // 256 KB packed bf16 weights

    pack_w_kernel<<<64, 256, 0, stream>>>(w_ref, wp);
    const int grid = (NN + BM - 1) / BM;          // 1563
    gamlp_main<<<grid, 256, 0, stream>>>(xs, wp, b_ref, w_att, b_att, alpha, out);
}

// Round 5
// 160.284 us; speedup vs baseline: 1.3278x; 1.0227x over previous
//
#include <hip/hip_runtime.h>

#define LL 8
#define NN 100000
#define HH 128
#define KT 1024
#define BM 64
#define NNHH (NN * HH)

typedef __attribute__((ext_vector_type(4))) float f32x4;
typedef __attribute__((ext_vector_type(8))) short bf16x8;
typedef __attribute__((ext_vector_type(8))) unsigned short u16x8;

__device__ __forceinline__ unsigned short f2bf(float f) {
    unsigned u = __float_as_uint(f);
    unsigned r = ((u >> 16) & 1u) + 0x7fffu;   // RNE
    return (unsigned short)((u + r) >> 16);
}

// Pre-pack w_ref (f32 [128 cols][1024 k]) -> bf16 in fragment order:
// wp[(k8*128 + col)*8 + e] = bf16(w_ref[col][k8*8+e]),  k8 = k/8.
__global__ __launch_bounds__(256) void pack_w_kernel(const float* __restrict__ w_ref,
                                                     unsigned short* __restrict__ wp) {
    int gid = blockIdx.x * 256 + threadIdx.x;   // 0..16383
    int col = gid >> 7;
    int k8  = gid & 127;
    const float* s = w_ref + (size_t)col * KT + (size_t)k8 * 8;
    float4 v0 = *reinterpret_cast<const float4*>(s);
    float4 v1 = *reinterpret_cast<const float4*>(s + 4);
    u16x8 p;
    p[0] = f2bf(v0.x); p[1] = f2bf(v0.y); p[2] = f2bf(v0.z); p[3] = f2bf(v0.w);
    p[4] = f2bf(v1.x); p[5] = f2bf(v1.y); p[6] = f2bf(v1.z); p[7] = f2bf(v1.w);
    *reinterpret_cast<u16x8*>(wp + (size_t)(k8 * 128 + col) * 8) = p;
}

// Block = 64 nodes, 4 waves; wave w covers all 64 nodes x cols [w*32, +32).
// K-loop: 8 steps of BK=128 (one layer/step), double-buffered A in LDS,
// T14 split staging, ONE barrier/step, B depth-1 prefetch.
// Wave 0 additionally accumulates acc_sx via a synthetic B whose only nonzero
// column at step s is wa_x -> column l of acc_sx = sx[l][node] (per-layer dot).
__global__ __launch_bounds__(256, 3)
void gamlp_main(const float* __restrict__ xs,
                const unsigned short* __restrict__ wp,
                const float* __restrict__ b_ref,
                const float* __restrict__ w_att,
                const float* __restrict__ b_att_p,
                const float* __restrict__ alpha_p,
                float* __restrict__ out)
{
    __shared__ unsigned short A_lds[2][BM * 128];   // 2 x 16 KB, XOR-swizzled slots
    __shared__ float sjk_lds[BM][4];
    __shared__ float sx_lds[LL][BM];                // 2 KB, wave0 writes

    const int tid  = threadIdx.x;
    const int lane = tid & 63;
    const int wave = tid >> 6;
    const int colq = lane & 15;
    const int kq   = lane >> 4;
    const int n0   = blockIdx.x * BM;

    const float alpha = *alpha_p;
    const float batt  = *b_att_p;

    // ---- staging map: thread covers rows rb+16i (i<4), 16B slot ks ----
    const int ks = tid & 15;
    const int rb = tid >> 4;
    const float* srcp[4];
    unsigned short* dst0p[4];
    unsigned short* dst1p[4];
    #pragma unroll
    for (int i = 0; i < 4; i++) {
        int row = rb + i * 16;
        srcp[i] = xs + (size_t)min(n0 + row, NN - 1) * HH + ks * 8;
        int off = row * 128 + ((ks ^ rb) * 8);     // slot swizzle: ks ^ (row&15)
        dst0p[i] = &A_lds[0][off];
        dst1p[i] = &A_lds[1][off];
    }

    // ---- B fragment pointers (packed bf16, L2-resident) ----
    const unsigned short* pB0 = wp + (size_t)(wave * 32 + colq) * 8;
    const unsigned short* pB1 = pB0 + 128;      // +16 cols

    const float wr0 = w_att[wave * 32 + colq],      wr1 = w_att[wave * 32 + 16 + colq];
    const float br0 = b_ref[wave * 32 + colq],      br1 = b_ref[wave * 32 + 16 + colq];

    // ---- wave-0 sx state: wa_x fragment (within-layer k = c*32 + kq*8 + e) ----
    u16x8 waxf[4];
    #pragma unroll
    for (int c = 0; c < 4; c++) {
        const float* w = w_att + HH + c * 32 + kq * 8;
        #pragma unroll
        for (int e = 0; e < 8; e++) waxf[c][e] = f2bf(w[e]);
    }
    f32x4 acc_sx[4];
    #pragma unroll
    for (int m = 0; m < 4; m++) acc_sx[m] = (f32x4){0,0,0,0};

    f32x4 acc[4][2];
    #pragma unroll
    for (int m = 0; m < 4; m++) { acc[m][0] = (f32x4){0,0,0,0}; acc[m][1] = (f32x4){0,0,0,0}; }

    f32x4 pf[8];
    // ---- prologue: stage step 0 into buf 0 ----
    #pragma unroll
    for (int i = 0; i < 4; i++) {
        pf[2*i]   = *reinterpret_cast<const f32x4*>(srcp[i]);
        pf[2*i+1] = *reinterpret_cast<const f32x4*>(srcp[i] + 4);
    }
    #pragma unroll
    for (int i = 0; i < 4; i++) {
        u16x8 p;
        #pragma unroll
        for (int e = 0; e < 4; e++) { p[e] = f2bf(pf[2*i][e]); p[e+4] = f2bf(pf[2*i+1][e]); }
        *reinterpret_cast<u16x8*>(dst0p[i]) = p;
    }
    __syncthreads();

    // ---- main loop: 8 steps of BK=128 (step == layer) ----
    #pragma unroll
    for (int s = 0; s < 8; s++) {
        const int cur = s & 1;
        // (1) T14 issue-early: next step's global loads
        if (s < 7) {
            const size_t g = (size_t)(s + 1) * NNHH;
            #pragma unroll
            for (int i = 0; i < 4; i++) {
                pf[2*i]   = *reinterpret_cast<const f32x4*>(srcp[i] + g);
                pf[2*i+1] = *reinterpret_cast<const f32x4*>(srcp[i] + g + 4);
            }
        }
        // (2) compute current step: LDS A-frags + B (depth-1 prefetch) + MFMA
        const int k8base = s * 16;
        bf16x8 b0c = *reinterpret_cast<const bf16x8*>(pB0 + (size_t)(k8base + kq) * 1024);
        bf16x8 b1c = *reinterpret_cast<const bf16x8*>(pB1 + (size_t)(k8base + kq) * 1024);
        #pragma unroll
        for (int c = 0; c < 4; c++) {
            bf16x8 b0n, b1n;
            if (c < 3) {
                const size_t boff = (size_t)(k8base + (c + 1) * 4 + kq) * 1024;
                b0n = *reinterpret_cast<const bf16x8*>(pB0 + boff);
                b1n = *reinterpret_cast<const bf16x8*>(pB1 + boff);
            }
            bf16x8 af[4];
            #pragma unroll
            for (int m = 0; m < 4; m++) {
                int row = m * 16 + colq;
                af[m] = *reinterpret_cast<const bf16x8*>(
                    &A_lds[cur][row * 128 + (((c * 4 + kq) ^ colq) * 8)]);
            }
            #pragma unroll
            for (int m = 0; m < 4; m++) {
                acc[m][0] = __builtin_amdgcn_mfma_f32_16x16x32_bf16(af[m], b0c, acc[m][0], 0, 0, 0);
                acc[m][1] = __builtin_amdgcn_mfma_f32_16x16x32_bf16(af[m], b1c, acc[m][1], 0, 0, 0);
            }
            if (wave == 0) {
                // synthetic B: only column s nonzero (= wa_x chunk for this c)
                u16x8 bz = {0,0,0,0,0,0,0,0};
                u16x8 bsx = (colq == s) ? waxf[c] : bz;
                #pragma unroll
                for (int m = 0; m < 4; m++)
                    acc_sx[m] = __builtin_amdgcn_mfma_f32_16x16x32_bf16(
                        reinterpret_cast<bf16x8&>(bsx), af[m], acc_sx[m], 0, 0, 0) ;
            }
            b0c = b0n; b1c = b1n;
        }
        // (3) write-late: convert + ds_write into the other buffer
        if (s < 7) {
            #pragma unroll
            for (int i = 0; i < 4; i++) {
                u16x8 p;
                #pragma unroll
                for (int e = 0; e < 4; e++) { p[e] = f2bf(pf[2*i][e]); p[e+4] = f2bf(pf[2*i+1][e]); }
                *reinterpret_cast<u16x8*>((cur ? dst0p : dst1p)[i]) = p;
            }
        }
        __syncthreads();
    }

    // NOTE on acc_sx operand order: mfma(A,B,C) computes D[i][j] = sum_k A[i,k]*B[k,j]
    // with A-frag rows indexed by colq and D cols by colq. We passed (bsx, af):
    // bsx as "A" has row colq == s nonzero = wa_x; af as "B". Then
    // D[row=colq==l ?][col] ... D[l][node]: lane colq holds col=colq of D = node?
    // Fragment symmetry: D[r?]: col = colq, row = kq*4+r. With operands swapped,
    // roles of node/layer swap: acc_sx: col(colq) = D-col = node-frag? Careful:
    // af as B-operand: B[k][j] frag at lane(colq,kq) = af elements = A_lds row
    // (m*16+colq) -> j = m-block col index = node. So D[i=layer][j=node],
    // D-frag: col = colq -> node? No: col index j = colq only if B cols map colq.
    // B-frag layout: B[k = kq*8+e_k][col = colq]. af[m][e] = A_lds[node=m*16+colq][k],
    // i.e. col(colq) = node, k = kq*8.. -> D[row=i][col=node(colq)],
    // row from bsx-as-A: A[row=colq? NO: A-frag: A[row = colq][k = kq*8+e].
    // bsx nonzero at colq==s -> A[row=s] = wa_x -> D[s][node].
    // D-frag: D[row = kq*4 + r][col = colq]: row indexes bsx's rows (layers),
    // col indexes af's cols (nodes)... but nodes span 64 via m -> acc_sx[m],
    // and D cols are 16 (colq) vs nodes 16 per m ✓: acc_sx[m][r] =
    // sx[layer = kq*4 + r][node = m*16 + colq]  (layers 0..7 live in kq<2).
    if (wave == 0 && kq < 2) {
        #pragma unroll
        for (int m = 0; m < 4; m++)
            #pragma unroll
            for (int r = 0; r < 4; r++)
                sx_lds[kq * 4 + r][m * 16 + colq] = acc_sx[m][r];
    }

    // ---- sjk: sum over this wave's 32 cols of prelu(jk + b_ref) * wa_ref ----
    // D layout: col = wave*32 + n*16 + colq, node = m*16 + kq*4 + r
    #pragma unroll
    for (int m = 0; m < 4; m++) {
        float sr[4];
        #pragma unroll
        for (int r = 0; r < 4; r++) {
            float v0 = acc[m][0][r] + br0;  v0 = (v0 >= 0.f) ? v0 : alpha * v0;
            float v1 = acc[m][1][r] + br1;  v1 = (v1 >= 0.f) ? v1 : alpha * v1;
            float sv = v0 * wr0 + v1 * wr1;
            sv += __shfl_xor(sv, 1);
            sv += __shfl_xor(sv, 2);
            sv += __shfl_xor(sv, 4);
            sv += __shfl_xor(sv, 8);
            sr[r] = sv;
        }
        if (colq == 0) {
            #pragma unroll
            for (int r = 0; r < 4; r++)
                sjk_lds[m * 16 + kq * 4 + r][wave] = sr[r];
        }
    }
    __syncthreads();

    // ---- light epilogue: scores from LDS + softmax + weighted sum ----
    #pragma unroll
    for (int i = 0; i < 8; i++) {
        int f = tid + i * 256;          // 0..2047
        int node = f >> 5;              // 0..63
        int q = (f & 31) << 2;          // 0..124
        int ng = n0 + node;
        int ngc = min(ng, NN - 1);
        const float* base = xs + (size_t)ngc * HH + q;
        float sjk = sjk_lds[node][0] + sjk_lds[node][1] + sjk_lds[node][2] + sjk_lds[node][3];
        float sc[LL], mx = 0.f;
        #pragma unroll
        for (int l = 0; l < LL; l++) {
            float sv = sjk + sx_lds[l][node] + batt;
            sv = fmaxf(sv, 0.f);
            sc[l] = sv;
            mx = fmaxf(mx, sv);
        }
        float den = 0.f;
        #pragma unroll
        for (int l = 0; l < LL; l++) { sc[l] = __expf(sc[l] - mx); den += sc[l]; }
        float inv = 1.f / den;
        f32x4 o = (f32x4){0.f, 0.f, 0.f, 0.f};
        #pragma unroll
        for (int l = 0; l < LL; l++) {
            f32x4 v = *reinterpret_cast<const f32x4*>(base + (size_t)l * NNHH);
            o += (sc[l] * inv) * v;
        }
        if (ng < NN)
            *reinterpret_cast<f32x4*>(out + (size_t)ng * HH + q) = o;
    }
}

extern "C" void kernel_launch(void* const* d_in, const int* in_sizes, int n_in,
                              void* d_out, int out_size, void* d_ws, size_t ws_size,
                              hipStream_t stream) {
    const float* xs     = (const float*)d_in[0];
    const float* w_ref  = (const float*)d_in[1];
    const float* b_ref  = (const float*)d_in[2];
    const float* w_att  = (const float*)d_in[3];
    const float* b_att  = (const float*)d_in[4];
    const float* alpha  = (const float*)d_in[5];
    float* out = (float*)d_out;
    unsigned short* wp = (unsigned short*)d_ws;   // 256 KB packed bf16 weights

    pack_w_kernel<<<64, 256, 0, stream>>>(w_ref, wp);
    const int grid = (NN + BM - 1) / BM;          // 1563
    gamlp_main<<<grid, 256, 0, stream>>>(xs, wp, b_ref, w_att, b_att, alpha, out);
}

// Round 6
// 155.470 us; speedup vs baseline: 1.3690x; 1.0310x over previous
//
#include <hip/hip_runtime.h>

#define LL 8
#define NN 100000
#define HH 128
#define KT 1024
#define BM 64
#define NNHH (NN * HH)

typedef __attribute__((ext_vector_type(4))) float f32x4;
typedef __attribute__((ext_vector_type(8))) short bf16x8;
typedef __attribute__((ext_vector_type(8))) unsigned short u16x8;

__device__ __forceinline__ unsigned short f2bf(float f) {
    unsigned u = __float_as_uint(f);
    unsigned r = ((u >> 16) & 1u) + 0x7fffu;   // RNE
    return (unsigned short)((u + r) >> 16);
}

// Pre-pack w_ref (f32 [128 cols][1024 k]) -> bf16 in fragment order:
// wp[(k8*128 + col)*8 + e] = bf16(w_ref[col][k8*8+e]),  k8 = k/8.
__global__ __launch_bounds__(256) void pack_w_kernel(const float* __restrict__ w_ref,
                                                     unsigned short* __restrict__ wp) {
    int gid = blockIdx.x * 256 + threadIdx.x;   // 0..16383
    int col = gid >> 7;
    int k8  = gid & 127;
    const float* s = w_ref + (size_t)col * KT + (size_t)k8 * 8;
    float4 v0 = *reinterpret_cast<const float4*>(s);
    float4 v1 = *reinterpret_cast<const float4*>(s + 4);
    u16x8 p;
    p[0] = f2bf(v0.x); p[1] = f2bf(v0.y); p[2] = f2bf(v0.z); p[3] = f2bf(v0.w);
    p[4] = f2bf(v1.x); p[5] = f2bf(v1.y); p[6] = f2bf(v1.z); p[7] = f2bf(v1.w);
    *reinterpret_cast<u16x8*>(wp + (size_t)(k8 * 128 + col) * 8) = p;
}

// Block = 64 nodes, 4 waves; wave w covers all 64 nodes x cols [w*32, +32).
// K-loop: 8 steps of BK=128 (one layer/step), TRIPLE-buffered A in LDS,
// 2-step-deep register prefetch. Barriers are raw s_barrier preceded by
// lgkmcnt(0) ONLY -> global loads stay in flight across barriers (no vmcnt
// drain, unlike __syncthreads). sx computed in f32 during the convert phase.
__global__ __launch_bounds__(256, 3)
void gamlp_main(const float* __restrict__ xs,
                const unsigned short* __restrict__ wp,
                const float* __restrict__ b_ref,
                const float* __restrict__ w_att,
                const float* __restrict__ b_att_p,
                const float* __restrict__ alpha_p,
                float* __restrict__ out)
{
    __shared__ unsigned short A_lds[3 * BM * 128];  // 3 x 16 KB, XOR-swizzled slots
    __shared__ float sjk_lds[BM][4];
    __shared__ float sx_lds[LL][BM];                // 2 KB

    const int tid  = threadIdx.x;
    const int lane = tid & 63;
    const int wave = tid >> 6;
    const int colq = lane & 15;
    const int kq   = lane >> 4;
    const int n0   = blockIdx.x * BM;

    const float alpha = *alpha_p;
    const float batt  = *b_att_p;

    // ---- staging map: thread covers rows rb+16i (i<4), 16B slot ks ----
    const int ks = tid & 15;
    const int rb = tid >> 4;
    const float* srcp[4];
    int dstoff[4];
    #pragma unroll
    for (int i = 0; i < 4; i++) {
        int row = rb + i * 16;
        srcp[i] = xs + (size_t)min(n0 + row, NN - 1) * HH + ks * 8;
        dstoff[i] = row * 128 + ((ks ^ rb) * 8);    // slot swizzle: ks ^ (row&15)
    }

    // wa_x slice for this thread's k-slot (f32)
    const f32x4 wax0 = *reinterpret_cast<const f32x4*>(w_att + HH + ks * 8);
    const f32x4 wax1 = *reinterpret_cast<const f32x4*>(w_att + HH + ks * 8 + 4);

    // ---- B fragment pointers (packed bf16, L2-resident) ----
    const unsigned short* pB0 = wp + (size_t)(wave * 32 + colq) * 8;
    const unsigned short* pB1 = pB0 + 128;      // +16 cols

    const float wr0 = w_att[wave * 32 + colq],      wr1 = w_att[wave * 32 + 16 + colq];
    const float br0 = b_ref[wave * 32 + colq],      br1 = b_ref[wave * 32 + 16 + colq];

    f32x4 acc[4][2];
    #pragma unroll
    for (int m = 0; m < 4; m++) { acc[m][0] = (f32x4){0,0,0,0}; acc[m][1] = (f32x4){0,0,0,0}; }

    f32x4 pf[2][8];

#define LOADS(SET, STEP) do {                                                    \
    const size_t g_ = (size_t)(STEP) * NNHH;                                     \
    _Pragma("unroll")                                                            \
    for (int i_ = 0; i_ < 4; i_++) {                                             \
        pf[SET][2*i_]   = *reinterpret_cast<const f32x4*>(srcp[i_] + g_);        \
        pf[SET][2*i_+1] = *reinterpret_cast<const f32x4*>(srcp[i_] + g_ + 4);    \
    }                                                                            \
} while (0)

    // convert pf[SET] (layer LAY data) -> bf16 into buffer BUF; also sx[LAY] in f32
#define CONVERT_WRITE(SET, BUF, LAY) do {                                        \
    float part_[4];                                                              \
    _Pragma("unroll")                                                            \
    for (int i_ = 0; i_ < 4; i_++) {                                             \
        f32x4 a_ = pf[SET][2*i_], b_ = pf[SET][2*i_+1];                          \
        part_[i_] = a_[0]*wax0[0] + a_[1]*wax0[1] + a_[2]*wax0[2] + a_[3]*wax0[3]\
                  + b_[0]*wax1[0] + b_[1]*wax1[1] + b_[2]*wax1[2] + b_[3]*wax1[3];\
    }                                                                            \
    _Pragma("unroll")                                                            \
    for (int i_ = 0; i_ < 4; i_++) {                                             \
        part_[i_] += __shfl_xor(part_[i_], 1);                                   \
        part_[i_] += __shfl_xor(part_[i_], 2);                                   \
        part_[i_] += __shfl_xor(part_[i_], 4);                                   \
        part_[i_] += __shfl_xor(part_[i_], 8);                                   \
    }                                                                            \
    if (ks == 0) {                                                               \
        _Pragma("unroll")                                                        \
        for (int i_ = 0; i_ < 4; i_++) sx_lds[LAY][rb + 16*i_] = part_[i_];      \
    }                                                                            \
    _Pragma("unroll")                                                            \
    for (int i_ = 0; i_ < 4; i_++) {                                             \
        u16x8 pk_;                                                               \
        _Pragma("unroll")                                                        \
        for (int e_ = 0; e_ < 4; e_++) {                                         \
            pk_[e_]   = f2bf(pf[SET][2*i_][e_]);                                 \
            pk_[e_+4] = f2bf(pf[SET][2*i_+1][e_]);                               \
        }                                                                        \
        *reinterpret_cast<u16x8*>(&A_lds[(BUF) * 8192 + dstoff[i_]]) = pk_;      \
    }                                                                            \
} while (0)

#define LGKM_BARRIER() do {                                                      \
    asm volatile("s_waitcnt lgkmcnt(0)" ::: "memory");                           \
    __builtin_amdgcn_s_barrier();                                                \
} while (0)

    // ---- prologue ----
    LOADS(0, 0);
    LOADS(1, 1);
    CONVERT_WRITE(0, 0, 0);     // layer 0 -> buf 0 (waits only the first 8 loads)
    LGKM_BARRIER();

    // ---- main loop: 8 steps (step == layer), fully unrolled ----
    #pragma unroll
    for (int s = 0; s < 8; s++) {
        if (s + 2 < 8) LOADS(s & 1, s + 2);
        if (s + 1 < 8) CONVERT_WRITE((s + 1) & 1, (s + 1) % 3, s + 1);
        // MFMA on buf s%3
        const int bufo = (s % 3) * 8192;
        const int k8base = s * 16;
        bf16x8 b0c = *reinterpret_cast<const bf16x8*>(pB0 + (size_t)(k8base + kq) * 1024);
        bf16x8 b1c = *reinterpret_cast<const bf16x8*>(pB1 + (size_t)(k8base + kq) * 1024);
        #pragma unroll
        for (int c = 0; c < 4; c++) {
            bf16x8 b0n, b1n;
            if (c < 3) {
                const size_t boff = (size_t)(k8base + (c + 1) * 4 + kq) * 1024;
                b0n = *reinterpret_cast<const bf16x8*>(pB0 + boff);
                b1n = *reinterpret_cast<const bf16x8*>(pB1 + boff);
            }
            bf16x8 af[4];
            #pragma unroll
            for (int m = 0; m < 4; m++) {
                int row = m * 16 + colq;
                af[m] = *reinterpret_cast<const bf16x8*>(
                    &A_lds[bufo + row * 128 + (((c * 4 + kq) ^ colq) * 8)]);
            }
            #pragma unroll
            for (int m = 0; m < 4; m++) {
                acc[m][0] = __builtin_amdgcn_mfma_f32_16x16x32_bf16(af[m], b0c, acc[m][0], 0, 0, 0);
                acc[m][1] = __builtin_amdgcn_mfma_f32_16x16x32_bf16(af[m], b1c, acc[m][1], 0, 0, 0);
            }
            b0c = b0n; b1c = b1n;
        }
        LGKM_BARRIER();
    }

    // ---- sjk: sum over this wave's 32 cols of prelu(jk + b_ref) * wa_ref ----
    // D layout: col = wave*32 + n*16 + colq, node = m*16 + kq*4 + r
    #pragma unroll
    for (int m = 0; m < 4; m++) {
        float sr[4];
        #pragma unroll
        for (int r = 0; r < 4; r++) {
            float v0 = acc[m][0][r] + br0;  v0 = (v0 >= 0.f) ? v0 : alpha * v0;
            float v1 = acc[m][1][r] + br1;  v1 = (v1 >= 0.f) ? v1 : alpha * v1;
            float sv = v0 * wr0 + v1 * wr1;
            sv += __shfl_xor(sv, 1);
            sv += __shfl_xor(sv, 2);
            sv += __shfl_xor(sv, 4);
            sv += __shfl_xor(sv, 8);
            sr[r] = sv;
        }
        if (colq == 0) {
            #pragma unroll
            for (int r = 0; r < 4; r++)
                sjk_lds[m * 16 + kq * 4 + r][wave] = sr[r];
        }
    }
    __syncthreads();

    // ---- light epilogue: scores from LDS + softmax + weighted sum ----
    #pragma unroll
    for (int i = 0; i < 8; i++) {
        int f = tid + i * 256;          // 0..2047
        int node = f >> 5;              // 0..63
        int q = (f & 31) << 2;          // 0..124
        int ng = n0 + node;
        int ngc = min(ng, NN - 1);
        const float* base = xs + (size_t)ngc * HH + q;
        float sjk = sjk_lds[node][0] + sjk_lds[node][1] + sjk_lds[node][2] + sjk_lds[node][3];
        float sc[LL], mx = 0.f;
        #pragma unroll
        for (int l = 0; l < LL; l++) {
            float sv = sjk + sx_lds[l][node] + batt;
            sv = fmaxf(sv, 0.f);
            sc[l] = sv;
            mx = fmaxf(mx, sv);
        }
        float den = 0.f;
        #pragma unroll
        for (int l = 0; l < LL; l++) { sc[l] = __expf(sc[l] - mx); den += sc[l]; }
        float inv = 1.f / den;
        f32x4 o = (f32x4){0.f, 0.f, 0.f, 0.f};
        #pragma unroll
        for (int l = 0; l < LL; l++) {
            f32x4 v = *reinterpret_cast<const f32x4*>(base + (size_t)l * NNHH);
            o += (sc[l] * inv) * v;
        }
        if (ng < NN)
            *reinterpret_cast<f32x4*>(out + (size_t)ng * HH + q) = o;
    }
#undef LOADS
#undef CONVERT_WRITE
#undef LGKM_BARRIER
}

extern "C" void kernel_launch(void* const* d_in, const int* in_sizes, int n_in,
                              void* d_out, int out_size, void* d_ws, size_t ws_size,
                              hipStream_t stream) {
    const float* xs     = (const float*)d_in[0];
    const float* w_ref  = (const float*)d_in[1];
    const float* b_ref  = (const float*)d_in[2];
    const float* w_att  = (const float*)d_in[3];
    const float* b_att  = (const float*)d_in[4];
    const float* alpha  = (const float*)d_in[5];
    float* out = (float*)d_out;
    unsigned short* wp = (unsigned short*)d_ws;   // 256 KB packed bf16 weights

    pack_w_kernel<<<64, 256, 0, stream>>>(w_ref, wp);
    const int grid = (NN + BM - 1) / BM;          // 1563
    gamlp_main<<<grid, 256, 0, stream>>>(xs, wp, b_ref, w_att, b_att, alpha, out);
}

// Round 7
// 123.571 us; speedup vs baseline: 1.7224x; 1.2581x over previous
//
#include <hip/hip_runtime.h>

#define LL 8
#define NN 100000
#define HH 128
#define KT 1024
#define BM 32
#define NNHH (NN * HH)

typedef __attribute__((ext_vector_type(4))) float f32x4;
typedef __attribute__((ext_vector_type(8))) short bf16x8;
typedef __attribute__((ext_vector_type(8))) unsigned short u16x8;

__device__ __forceinline__ unsigned short f2bf(float f) {
    unsigned u = __float_as_uint(f);
    unsigned r = ((u >> 16) & 1u) + 0x7fffu;   // RNE
    return (unsigned short)((u + r) >> 16);
}
__device__ __forceinline__ float bf2f(unsigned short s) {
    return __uint_as_float(((unsigned)s) << 16);
}

// Pre-pack w_ref (f32 [128 cols][1024 k]) -> bf16 in fragment order:
// wp[(k8*128 + col)*8 + e] = bf16(w_ref[col][k8*8+e]),  k8 = k/8.
__global__ __launch_bounds__(256) void pack_w_kernel(const float* __restrict__ w_ref,
                                                     unsigned short* __restrict__ wp) {
    int gid = blockIdx.x * 256 + threadIdx.x;   // 0..16383
    int col = gid >> 7;
    int k8  = gid & 127;
    const float* s = w_ref + (size_t)col * KT + (size_t)k8 * 8;
    float4 v0 = *reinterpret_cast<const float4*>(s);
    float4 v1 = *reinterpret_cast<const float4*>(s + 4);
    u16x8 p;
    p[0] = f2bf(v0.x); p[1] = f2bf(v0.y); p[2] = f2bf(v0.z); p[3] = f2bf(v0.w);
    p[4] = f2bf(v1.x); p[5] = f2bf(v1.y); p[6] = f2bf(v1.z); p[7] = f2bf(v1.w);
    *reinterpret_cast<u16x8*>(wp + (size_t)(k8 * 128 + col) * 8) = p;
}

// Block = 32 nodes (exact: 3125*32 = 100000), 4 waves; wave w: 32 nodes x cols [w*32,+32).
// ALL 8 layers' bf16 A-tiles stay resident in LDS (8 x 8KB). xs is read from HBM
// exactly ONCE; the weighted-sum epilogue reads bf16 from LDS, not global.
// 3-set register prefetch (~2.5 steps deep), lgkm-only barriers (loads stay in
// flight across s_barrier). sx computed in f32 during the convert phase.
__global__ __launch_bounds__(256, 2)
void gamlp_main(const float* __restrict__ xs,
                const unsigned short* __restrict__ wp,
                const float* __restrict__ b_ref,
                const float* __restrict__ w_att,
                const float* __restrict__ b_att_p,
                const float* __restrict__ alpha_p,
                float* __restrict__ out)
{
    __shared__ unsigned short A_lds[LL][BM * 128];  // 8 x 8KB = 64KB, XOR-swizzled slots
    __shared__ float sjk_lds[BM][4];
    __shared__ float sx_lds[LL][BM];

    const int tid  = threadIdx.x;
    const int lane = tid & 63;
    const int wave = tid >> 6;
    const int colq = lane & 15;
    const int kq   = lane >> 4;
    const int n0   = blockIdx.x * BM;

    const float alpha = *alpha_p;
    const float batt  = *b_att_p;

    // ---- staging map: thread covers (row0, slot) and (row1 = row0+16, slot) ----
    const int slot = tid & 15;
    const int row0 = tid >> 4;          // 0..15
    const int row1 = row0 + 16;        // 16..31
    const float* src0 = xs + (size_t)(n0 + row0) * HH + slot * 8;
    const float* src1 = xs + (size_t)(n0 + row1) * HH + slot * 8;
    const int doff0 = row0 * 128 + ((slot ^ (row0 & 15)) * 8);
    const int doff1 = row1 * 128 + ((slot ^ (row1 & 15)) * 8);

    // wa_x slice for this thread's k-slot (f32)
    const f32x4 wax0 = *reinterpret_cast<const f32x4*>(w_att + HH + slot * 8);
    const f32x4 wax1 = *reinterpret_cast<const f32x4*>(w_att + HH + slot * 8 + 4);

    // ---- B fragment pointers (packed bf16, L2-resident) ----
    const unsigned short* pB0 = wp + (size_t)(wave * 32 + colq) * 8;
    const unsigned short* pB1 = pB0 + 128;      // +16 cols

    const float wr0 = w_att[wave * 32 + colq],      wr1 = w_att[wave * 32 + 16 + colq];
    const float br0 = b_ref[wave * 32 + colq],      br1 = b_ref[wave * 32 + 16 + colq];

    f32x4 acc[2][2];
    #pragma unroll
    for (int m = 0; m < 2; m++) { acc[m][0] = (f32x4){0,0,0,0}; acc[m][1] = (f32x4){0,0,0,0}; }

    f32x4 pf[3][4];

#define LOADS(SET, LAY) do {                                                     \
    const size_t g_ = (size_t)(LAY) * NNHH;                                      \
    pf[SET][0] = *reinterpret_cast<const f32x4*>(src0 + g_);                     \
    pf[SET][1] = *reinterpret_cast<const f32x4*>(src0 + g_ + 4);                 \
    pf[SET][2] = *reinterpret_cast<const f32x4*>(src1 + g_);                     \
    pf[SET][3] = *reinterpret_cast<const f32x4*>(src1 + g_ + 4);                 \
} while (0)

#define CONVERT_WRITE(SET, LAY) do {                                             \
    float pa_ = pf[SET][0][0]*wax0[0] + pf[SET][0][1]*wax0[1]                    \
              + pf[SET][0][2]*wax0[2] + pf[SET][0][3]*wax0[3]                    \
              + pf[SET][1][0]*wax1[0] + pf[SET][1][1]*wax1[1]                    \
              + pf[SET][1][2]*wax1[2] + pf[SET][1][3]*wax1[3];                   \
    float pb_ = pf[SET][2][0]*wax0[0] + pf[SET][2][1]*wax0[1]                    \
              + pf[SET][2][2]*wax0[2] + pf[SET][2][3]*wax0[3]                    \
              + pf[SET][3][0]*wax1[0] + pf[SET][3][1]*wax1[1]                    \
              + pf[SET][3][2]*wax1[2] + pf[SET][3][3]*wax1[3];                   \
    pa_ += __shfl_xor(pa_, 1); pa_ += __shfl_xor(pa_, 2);                        \
    pa_ += __shfl_xor(pa_, 4); pa_ += __shfl_xor(pa_, 8);                        \
    pb_ += __shfl_xor(pb_, 1); pb_ += __shfl_xor(pb_, 2);                        \
    pb_ += __shfl_xor(pb_, 4); pb_ += __shfl_xor(pb_, 8);                        \
    if (slot == 0) { sx_lds[LAY][row0] = pa_; sx_lds[LAY][row1] = pb_; }         \
    u16x8 pk0_, pk1_;                                                            \
    _Pragma("unroll")                                                            \
    for (int e_ = 0; e_ < 4; e_++) {                                             \
        pk0_[e_]   = f2bf(pf[SET][0][e_]);                                       \
        pk0_[e_+4] = f2bf(pf[SET][1][e_]);                                       \
        pk1_[e_]   = f2bf(pf[SET][2][e_]);                                       \
        pk1_[e_+4] = f2bf(pf[SET][3][e_]);                                       \
    }                                                                            \
    *reinterpret_cast<u16x8*>(&A_lds[LAY][doff0]) = pk0_;                        \
    *reinterpret_cast<u16x8*>(&A_lds[LAY][doff1]) = pk1_;                        \
} while (0)

#define LGKM_BARRIER() do {                                                      \
    asm volatile("s_waitcnt lgkmcnt(0)" ::: "memory");                           \
    __builtin_amdgcn_s_barrier();                                                \
} while (0)

    // ---- prologue: 3 layers of loads in flight, convert layer 0 ----
    LOADS(0, 0);
    LOADS(1, 1);
    LOADS(2, 2);
    CONVERT_WRITE(0, 0);
    LGKM_BARRIER();

    // ---- main loop: 8 steps (step == layer), fully unrolled ----
    #pragma unroll
    for (int s = 0; s < 8; s++) {
        if (s + 3 < 8) LOADS((s + 3) % 3, s + 3);
        if (s + 1 < 8) CONVERT_WRITE((s + 1) % 3, s + 1);
        // MFMA on layer s's resident tile
        const int k8base = s * 16;
        bf16x8 b0c = *reinterpret_cast<const bf16x8*>(pB0 + (size_t)(k8base + kq) * 1024);
        bf16x8 b1c = *reinterpret_cast<const bf16x8*>(pB1 + (size_t)(k8base + kq) * 1024);
        #pragma unroll
        for (int c = 0; c < 4; c++) {
            bf16x8 b0n, b1n;
            if (c < 3) {
                const size_t boff = (size_t)(k8base + (c + 1) * 4 + kq) * 1024;
                b0n = *reinterpret_cast<const bf16x8*>(pB0 + boff);
                b1n = *reinterpret_cast<const bf16x8*>(pB1 + boff);
            }
            bf16x8 af[2];
            #pragma unroll
            for (int m = 0; m < 2; m++) {
                int row = m * 16 + colq;
                af[m] = *reinterpret_cast<const bf16x8*>(
                    &A_lds[s][row * 128 + (((c * 4 + kq) ^ colq) * 8)]);
            }
            #pragma unroll
            for (int m = 0; m < 2; m++) {
                acc[m][0] = __builtin_amdgcn_mfma_f32_16x16x32_bf16(af[m], b0c, acc[m][0], 0, 0, 0);
                acc[m][1] = __builtin_amdgcn_mfma_f32_16x16x32_bf16(af[m], b1c, acc[m][1], 0, 0, 0);
            }
            b0c = b0n; b1c = b1n;
        }
        LGKM_BARRIER();
    }

    // ---- sjk: sum over this wave's 32 cols of prelu(jk + b_ref) * wa_ref ----
    // D layout: col = wave*32 + n*16 + colq, node = m*16 + kq*4 + r
    #pragma unroll
    for (int m = 0; m < 2; m++) {
        float sr[4];
        #pragma unroll
        for (int r = 0; r < 4; r++) {
            float v0 = acc[m][0][r] + br0;  v0 = (v0 >= 0.f) ? v0 : alpha * v0;
            float v1 = acc[m][1][r] + br1;  v1 = (v1 >= 0.f) ? v1 : alpha * v1;
            float sv = v0 * wr0 + v1 * wr1;
            sv += __shfl_xor(sv, 1);
            sv += __shfl_xor(sv, 2);
            sv += __shfl_xor(sv, 4);
            sv += __shfl_xor(sv, 8);
            sr[r] = sv;
        }
        if (colq == 0) {
            #pragma unroll
            for (int r = 0; r < 4; r++)
                sjk_lds[m * 16 + kq * 4 + r][wave] = sr[r];
        }
    }
    __syncthreads();

    // ---- epilogue: softmax from LDS scores + weighted sum from LDS bf16 tiles ----
    // Thread handles (node=row0, slot) and (node=row1, slot); xs NOT re-read.
    #pragma unroll
    for (int h = 0; h < 2; h++) {
        const int node = h ? row1 : row0;
        const int boff = node * 128 + ((slot ^ (node & 15)) * 8);
        float sjk = sjk_lds[node][0] + sjk_lds[node][1] + sjk_lds[node][2] + sjk_lds[node][3];
        float sc[LL], mx = 0.f;
        #pragma unroll
        for (int l = 0; l < LL; l++) {
            float sv = sjk + sx_lds[l][node] + batt;
            sv = fmaxf(sv, 0.f);
            sc[l] = sv;
            mx = fmaxf(mx, sv);
        }
        float den = 0.f;
        #pragma unroll
        for (int l = 0; l < LL; l++) { sc[l] = __expf(sc[l] - mx); den += sc[l]; }
        float inv = 1.f / den;
        f32x4 o0 = (f32x4){0.f, 0.f, 0.f, 0.f};
        f32x4 o1 = (f32x4){0.f, 0.f, 0.f, 0.f};
        #pragma unroll
        for (int l = 0; l < LL; l++) {
            u16x8 v = *reinterpret_cast<const u16x8*>(&A_lds[l][boff]);
            float wl = sc[l] * inv;
            #pragma unroll
            for (int e = 0; e < 4; e++) {
                o0[e] += wl * bf2f(v[e]);
                o1[e] += wl * bf2f(v[e + 4]);
            }
        }
        float* op = out + (size_t)(n0 + node) * HH + slot * 8;
        *reinterpret_cast<f32x4*>(op)     = o0;
        *reinterpret_cast<f32x4*>(op + 4) = o1;
    }
#undef LOADS
#undef CONVERT_WRITE
#undef LGKM_BARRIER
}

extern "C" void kernel_launch(void* const* d_in, const int* in_sizes, int n_in,
                              void* d_out, int out_size, void* d_ws, size_t ws_size,
                              hipStream_t stream) {
    const float* xs     = (const float*)d_in[0];
    const float* w_ref  = (const float*)d_in[1];
    const float* b_ref  = (const float*)d_in[2];
    const float* w_att  = (const float*)d_in[3];
    const float* b_att  = (const float*)d_in[4];
    const float* alpha  = (const float*)d_in[5];
    float* out = (float*)d_out;
    unsigned short* wp = (unsigned short*)d_ws;   // 256 KB packed bf16 weights

    pack_w_kernel<<<64, 256, 0, stream>>>(w_ref, wp);
    const int grid = NN / BM;                     // 3125, exact
    gamlp_main<<<grid, 256, 0, stream>>>(xs, wp, b_ref, w_att, b_att, alpha, out);
}